// Round 6
// baseline (1392.733 us; speedup 1.0000x reference)
//
#include <hip/hip_runtime.h>
#include <stdint.h>

#define N_NODES 10000
#define N_EDGES 320000

using bf16x8 = __attribute__((ext_vector_type(8))) short;
using fp32x4 = __attribute__((ext_vector_type(4))) float;
using u16x4 = __attribute__((ext_vector_type(4))) unsigned short;
using i32x4 = __attribute__((ext_vector_type(4))) int;

__device__ __forceinline__ float bf2f(unsigned short u) {
  union { unsigned int i; float f; } v; v.i = ((unsigned int)u) << 16; return v.f;
}
__device__ __forceinline__ unsigned short f2bf(float f) {
  union { float f; unsigned int i; } v; v.f = f;
  unsigned int x = v.i;
  x += 0x7fffu + ((x >> 16) & 1u);
  return (unsigned short)(x >> 16);
}

// ---------------- internal bf16 arena (element offsets) ---------------------
#define A_POS 0
#define A_EA 20000
#define A_WP 340000
#define A_BP 340512
#define A_WA 340768
#define A_BA 341024
#define A_W1 341280
#define A_B1 537888
#define A_W2 538656
#define A_B2 735264
#define A_WE 736032
#define A_BE 998176
#define A_WS 999200
#define A_WT 1261344
#define A_WM1 1523488
#define A_BM1 1556384
#define A_AL 1556512
#define A_WM2 1556544
#define A_BM2 1556672
#define ARENA_USED 1556673
#define ARENA_TOT 1556736

__constant__ int g_off[19] = {A_POS, A_EA, A_WP, A_BP, A_WA, A_BA, A_W1, A_B1,
                              A_W2, A_B2, A_WE, A_BE, A_WS, A_WT, A_WM1,
                              A_BM1, A_AL, A_WM2, A_BM2};

struct Ptrs { const void* p[19]; };

// Dtype detector: fp32 read as bf16 halves yields ~47% |v|>100; bf16 never.
__global__ void k_detect(const unsigned short* wpraw, int* flag) {
  __shared__ int cnt;
  int tid = threadIdx.x;
  if (tid == 0) cnt = 0;
  __syncthreads();
  float v0 = bf2f(wpraw[tid]);
  float v1 = bf2f(wpraw[256 + tid]);
  int big = (fabsf(v0) > 100.f ? 1 : 0) + (fabsf(v1) > 100.f ? 1 : 0);
  atomicAdd(&cnt, big);
  __syncthreads();
  if (tid == 0) *flag = (cnt > 10) ? 1 : 0;  // 1 = fp32 inputs
}

// Normalize all float inputs into the bf16 arena (flattened grid).
__global__ void k_cast(Ptrs ptrs, const int* __restrict__ flag,
                       unsigned short* __restrict__ arena) {
  int a = blockIdx.x * 256 + threadIdx.x;
  if (a >= ARENA_USED) return;
  int z = 0;
#pragma unroll
  for (int j = 1; j < 19; ++j) if (a >= g_off[j]) z = j;
  int i = a - g_off[z];
  float v;
  if (*flag) v = ((const float*)ptrs.p[z])[i];
  else       v = bf2f(((const unsigned short*)ptrs.p[z])[i]);
  arena[a] = f2bf(v);
}

// ---------------------------------------------------------------------------
// Weight prep: transpose [K,N] -> n-major [N,K] (row = out-col, 512B rows).
// nodeBT per layer l<3: [W1T|W2T|WsT|WtT] (1024x256); l==3: [WsT|WtT].
// ---------------------------------------------------------------------------
__global__ void k_prep(const unsigned short* __restrict__ arena,
                       unsigned short* nodeBT, unsigned short* WeT,
                       unsigned short* Wm1T, unsigned short* biascat) {
  int z = blockIdx.z;
  int i = blockIdx.x * 256 + threadIdx.x;
  if (z == 19) {  // bias concat: 3 x [b1|b2|0|0] (1024) then 512 zeros
    if (i < 3072) {
      int l = i >> 10, j = i & 1023;
      unsigned short v = 0;
      if (j < 256) v = arena[A_B1 + l * 256 + j];
      else if (j < 512) v = arena[A_B2 + l * 256 + (j - 256)];
      biascat[i] = v;
    } else if (i < 3584) {
      biascat[i] = 0;
    }
    return;
  }
  const unsigned short* src; unsigned short* dst; int srcN = 256;
  if (z < 3)       {                 src = arena + A_W1 + z * 65536; dst = nodeBT + z * 262144; }
  else if (z < 6)  { int l = z - 3;  src = arena + A_W2 + l * 65536; dst = nodeBT + l * 262144 + 65536; }
  else if (z < 10) { int l = z - 6;  src = arena + A_WS + l * 65536;
                     dst = (l < 3) ? nodeBT + l * 262144 + 131072 : nodeBT + 786432; }
  else if (z < 14) { int l = z - 10; src = arena + A_WT + l * 65536;
                     dst = (l < 3) ? nodeBT + l * 262144 + 196608 : nodeBT + 786432 + 65536; }
  else if (z < 18) { int l = z - 14; src = arena + A_WE + l * 65536; dst = WeT + l * 65536; }
  else             { src = arena + A_WM1; dst = Wm1T; srcN = 128; }
  if (i < srcN * 256) {
    int k = i & 255, n = i >> 8;
    dst[i] = src[k * srcN + n];  // dst[n][k] = src[k][n]
  }
}

// x0 = pos @ Wp + bp (K=2), fp32 master + bf16 copy
__global__ void k_init_x(const unsigned short* __restrict__ arena,
                         float* __restrict__ xf, unsigned short* __restrict__ xbf) {
  int n = blockIdx.x, c = threadIdx.x;
  float p0 = bf2f(arena[A_POS + 2 * n]), p1 = bf2f(arena[A_POS + 2 * n + 1]);
  float v = fmaf(p0, bf2f(arena[A_WP + c]),
                 fmaf(p1, bf2f(arena[A_WP + 256 + c]), bf2f(arena[A_BP + c])));
  long idx = ((long)n << 8) + c;
  xf[idx] = v;
  xbf[idx] = f2bf(v);
}

// ---------------- CSR build (by dst). e lives in CSR row order everywhere ---
__global__ void k_hist(const int* __restrict__ dstA, int* __restrict__ deg) {
  int i = blockIdx.x * 256 + threadIdx.x;
  if (i < N_EDGES) {
    int d = dstA[i];
    if ((unsigned)d < N_NODES) atomicAdd(&deg[d], 1);
  }
}

__global__ void k_scan(const int* __restrict__ deg, int* __restrict__ rowptr,
                       int* __restrict__ cursor) {
  __shared__ int part[256];
  int tid = threadIdx.x;
  int base = tid * 40;
  int s = 0;
  for (int i = 0; i < 40; ++i) {
    int idx = base + i;
    if (idx < N_NODES) s += deg[idx];
  }
  part[tid] = s;
  __syncthreads();
  if (tid == 0) {
    int run = 0;
    for (int i = 0; i < 256; ++i) { int t = part[i]; part[i] = run; run += t; }
    rowptr[N_NODES] = run;
  }
  __syncthreads();
  int run = part[tid];
  for (int i = 0; i < 40; ++i) {
    int idx = base + i;
    if (idx < N_NODES) { rowptr[idx] = run; cursor[idx] = run; run += deg[idx]; }
  }
}

// Also emits csrc/cdst (endpoints in CSR order) and eaC (ea gathered to CSR).
__global__ void k_fill(const int* __restrict__ dstA, const int* __restrict__ srcA,
                       const unsigned short* __restrict__ arena,
                       int* __restrict__ cursor, int* __restrict__ eid,
                       int* __restrict__ csrc, int* __restrict__ cdst,
                       unsigned short* __restrict__ eaC) {
  int i = blockIdx.x * 256 + threadIdx.x;
  if (i < N_EDGES) {
    int d = dstA[i]; if ((unsigned)d >= N_NODES) d = 0;
    int p = atomicAdd(&cursor[d], 1);
    if ((unsigned)p < N_EDGES) {
      eid[p] = i;
      csrc[p] = srcA[i];
      cdst[p] = d;
      eaC[p] = arena[A_EA + i];
    }
  }
}

// ---------------------------------------------------------------------------
// Swapped-operand GEMM core: C^T = W^T * tile^T; MFMA reg dim = consecutive
// output cols. A-frag: WT row = out-col (512B rows). B-frag: LDS tile row.
// D lane(q,ll) reg r, [mt][nt]: outcol = colBase+mt*16+q*4+r, row = nt*16+ll.
// LDS pitch 528B -> <=2-way bank aliasing (free, m136).
// ---------------------------------------------------------------------------
#define SM_PITCH 528

template <bool NT>
__device__ __forceinline__ void stage_tile(char* smc, const unsigned short* src,
                                           long rowBase, long maxRow) {
  int tid = threadIdx.x;
#pragma unroll
  for (int it = 0; it < 16; ++it) {
    int lin = it * 256 + tid;       // 128 rows x 32 groups of 16B
    int row = lin >> 5, g = lin & 31;
    long rg = rowBase + row;
    if (rg > maxRow) rg = maxRow;
    const i32x4* p = (const i32x4*)((const char*)src + (rg << 9) + (g << 4));
    i32x4 v = NT ? __builtin_nontemporal_load(p) : *p;
    *(i32x4*)(smc + row * SM_PITCH + (g << 4)) = v;
  }
}

template <int MT>
__device__ __forceinline__ void gemm_swap(const char* smc, const unsigned short* WT,
                                          int colBase, fp32x4 (&acc)[MT][8]) {
  const int lane = threadIdx.x & 63;
  const int q = lane >> 4, ll = lane & 15;
#pragma unroll
  for (int ks = 0; ks < 8; ++ks) {
    bf16x8 a[MT];
#pragma unroll
    for (int mt = 0; mt < MT; ++mt) {
      int oc = colBase + mt * 16 + ll;
      a[mt] = *(const bf16x8*)((const char*)WT + ((long)oc << 9) + (ks << 6) + (q << 4));
    }
    bf16x8 b[8];
#pragma unroll
    for (int nt = 0; nt < 8; ++nt)
      b[nt] = *(const bf16x8*)(smc + (nt * 16 + ll) * SM_PITCH + (ks << 6) + (q << 4));
#pragma unroll
    for (int mt = 0; mt < MT; ++mt)
#pragma unroll
      for (int nt = 0; nt < 8; ++nt)
        acc[mt][nt] = __builtin_amdgcn_mfma_f32_16x16x32_bf16(a[mt], b[nt], acc[mt][nt], 0, 0, 0);
  }
}

// ---------------------------------------------------------------------------
// Edge update (CSR row order): e = e + relu(e @ We + XWs[src] + XWt[dst] + be).
// Latency plan: indices + all 32 random xs-gathers are ISSUED before the
// __syncthreads barrier, so their latency overlaps the barrier's mandatory
// vmcnt(0) drain of the staging loads; the GEMM then runs with a clean queue
// and the epilogue consumes xs from registers (xt stays inline: dst-sorted
// -> same-row L1 broadcast). Results written back into the LDS tile, then one
// coalesced full-line NT writeback (no partial-line write amplification).
// ---------------------------------------------------------------------------
template <bool FIRST>
__global__ __launch_bounds__(256, 2) void k_edge(
    unsigned short* __restrict__ e, const unsigned short* __restrict__ WT,
    const unsigned short* __restrict__ XW, int xw_pitch, int xs_off, int xt_off,
    const unsigned short* __restrict__ bePtr, const unsigned short* __restrict__ arena,
    const unsigned short* __restrict__ eaC,
    const int* __restrict__ csrc, const int* __restrict__ cdst) {
  __shared__ int4 sm4[128 * 33];
  char* smc = (char*)sm4;
  const long tileBase = (long)blockIdx.x * 128;
  const int tid = threadIdx.x;
  const int wave = tid >> 6, lane = tid & 63;
  const int q = lane >> 4, ll = lane & 15;
  const int colBase = wave * 64;

  if (FIRST) {
#pragma unroll
    for (int it = 0; it < 16; ++it) {
      int lin = it * 256 + tid;
      int row = lin >> 5, g = lin & 31;
      float eav = bf2f(eaC[tileBase + row]);
      int c0 = g * 8;
      bf16x8 ov;
#pragma unroll
      for (int j = 0; j < 8; ++j) {
        float f = fmaf(eav, bf2f(arena[A_WA + c0 + j]), bf2f(arena[A_BA + c0 + j]));
        ((unsigned short*)&ov)[j] = f2bf(f);
      }
      *(bf16x8*)(smc + row * SM_PITCH + (g << 4)) = ov;
    }
  } else {
    stage_tile<true>(smc, e, tileBase, N_EDGES - 1);
  }

  // Early index loads + xs-gather prefetch (overlaps barrier drain).
  int sn[8], dn[8];
#pragma unroll
  for (int nt = 0; nt < 8; ++nt) {
    long edge = tileBase + nt * 16 + ll;
    int s = csrc[edge]; if ((unsigned)s >= N_NODES) s = 0;
    int d = cdst[edge]; if ((unsigned)d >= N_NODES) d = 0;
    sn[nt] = s; dn[nt] = d;
  }
  u16x4 xsr[8][4];
#pragma unroll
  for (int nt = 0; nt < 8; ++nt) {
    const unsigned short* xsrow = XW + (long)sn[nt] * xw_pitch + xs_off + colBase;
#pragma unroll
    for (int mt = 0; mt < 4; ++mt)
      xsr[nt][mt] = *(const u16x4*)(xsrow + mt * 16 + q * 4);
  }
  __syncthreads();

  fp32x4 acc[4][8];
#pragma unroll
  for (int mt = 0; mt < 4; ++mt)
#pragma unroll
    for (int nt = 0; nt < 8; ++nt) acc[mt][nt] = 0.f;
  gemm_swap<4>(smc, WT, colBase, acc);

  float bec[4][4];
#pragma unroll
  for (int mt = 0; mt < 4; ++mt)
#pragma unroll
    for (int r = 0; r < 4; ++r) bec[mt][r] = bf2f(bePtr[colBase + mt * 16 + q * 4 + r]);

#pragma unroll
  for (int nt = 0; nt < 8; ++nt) {
    int el = nt * 16 + ll;
    const unsigned short* xtrow = XW + (long)dn[nt] * xw_pitch + xt_off + colBase;
#pragma unroll
    for (int mt = 0; mt < 4; ++mt) {
      int c0 = colBase + mt * 16 + q * 4;
      u16x4 xs = xsr[nt][mt];
      u16x4 xt = *(const u16x4*)(xtrow + mt * 16 + q * 4);
      u16x4* slot = (u16x4*)(smc + el * SM_PITCH + c0 * 2);
      u16x4 er = *slot;
      u16x4 o;
#pragma unroll
      for (int r = 0; r < 4; ++r) {
        float v = acc[mt][nt][r] + bf2f(xs[r]) + bf2f(xt[r]) + bec[mt][r];
        v = fmaxf(v, 0.f);
        o[r] = f2bf(bf2f(er[r]) + v);
      }
      *slot = o;  // update LDS in place (slot owned by this lane only)
    }
  }
  __syncthreads();
  // Coalesced full-line writeback: 16B/lane, 1KB contiguous per instruction.
#pragma unroll
  for (int it = 0; it < 16; ++it) {
    int lin = it * 256 + tid;
    int row = lin >> 5, g = lin & 31;
    i32x4 v = *(const i32x4*)(smc + row * SM_PITCH + (g << 4));
    __builtin_nontemporal_store(v, (i32x4*)((char*)e + ((tileBase + row) << 9) + (g << 4)));
  }
}

// Node-side GEMM: XW = x_bf @ [W1|W2|Ws|Wt] (+b1|b2|0|0), bf16 out.
__global__ __launch_bounds__(256, 2) void k_node_gemm(
    const unsigned short* __restrict__ xbf, const unsigned short* __restrict__ WT,
    const unsigned short* __restrict__ bias, unsigned short* __restrict__ out,
    int out_pitch) {
  __shared__ int4 sm4[128 * 33];
  char* smc = (char*)sm4;
  const long tileBase = (long)blockIdx.x * 128;
  stage_tile<false>(smc, xbf, tileBase, N_NODES - 1);
  __syncthreads();
  fp32x4 acc[4][8];
#pragma unroll
  for (int mt = 0; mt < 4; ++mt)
#pragma unroll
    for (int nt = 0; nt < 8; ++nt) acc[mt][nt] = 0.f;
  const int tid = threadIdx.x, wave = tid >> 6, lane = tid & 63;
  const int q = lane >> 4, ll = lane & 15;
  const int colBase = blockIdx.y * 256 + wave * 64;
  gemm_swap<4>(smc, WT, colBase, acc);

  float bs[4][4];
#pragma unroll
  for (int mt = 0; mt < 4; ++mt)
#pragma unroll
    for (int r = 0; r < 4; ++r) bs[mt][r] = bf2f(bias[colBase + mt * 16 + q * 4 + r]);

#pragma unroll
  for (int nt = 0; nt < 8; ++nt) {
    long nn = tileBase + nt * 16 + ll;
    if (nn >= N_NODES) continue;
#pragma unroll
    for (int mt = 0; mt < 4; ++mt) {
      int c0 = colBase + mt * 16 + q * 4;
      u16x4 o;
#pragma unroll
      for (int r = 0; r < 4; ++r) o[r] = f2bf(acc[mt][nt][r] + bs[mt][r]);
      *(u16x4*)(out + nn * out_pitch + c0) = o;
    }
  }
}

// agg[n] = sum_{CSR rows j of n} sigmoid(e[j]) * XW2[csrc[j]] — e sequential.
template <bool FIRST>
__global__ void k_agg(const int* __restrict__ rowptr, const int* __restrict__ csrc,
                      const unsigned short* __restrict__ e,
                      const unsigned short* __restrict__ eaC,
                      const unsigned short* __restrict__ arena,
                      const unsigned short* __restrict__ XW, int xw_pitch, int x2_off,
                      float* __restrict__ agg) {
  int n = blockIdx.x, c = threadIdx.x;
  int j0 = rowptr[n], j1 = rowptr[n + 1];
  float wac = 0.f, bac = 0.f;
  if (FIRST) { wac = bf2f(arena[A_WA + c]); bac = bf2f(arena[A_BA + c]); }
  float acc = 0.f;
  for (int j = j0; j < j1; ++j) {
    int sn = csrc[j]; if ((unsigned)sn >= N_NODES) sn = 0;
    float ev;
    if (FIRST) ev = fmaf(bf2f(eaC[j]), wac, bac);
    else ev = bf2f(__builtin_nontemporal_load(e + ((long)j << 8) + c));
    float gate = 1.f / (1.f + __expf(-ev));
    acc += gate * bf2f(XW[(long)sn * xw_pitch + x2_off + c]);
  }
  agg[((long)n << 8) + c] = acc;
}

// x += relu(xW1+b1 + agg); refresh bf16 copy
__global__ void k_node_update(float* __restrict__ xf, unsigned short* __restrict__ xbf,
                              const unsigned short* __restrict__ XW,
                              const float* __restrict__ agg) {
  int n = blockIdx.x, c = threadIdx.x;
  long idx = ((long)n << 8) + c;
  float t = bf2f(XW[((long)n << 10) + c]) + agg[idx];
  float nx = xf[idx] + fmaxf(t, 0.f);
  xf[idx] = nx;
  xbf[idx] = f2bf(nx);
}

// Final MLP (CSR rows): out[eid[j]] = prelu(e@Wm1[:256]+eaC*Wm1[256]+bm1)@Wm2+bm2
__global__ __launch_bounds__(256, 2) void k_mlp(
    const unsigned short* __restrict__ e, const unsigned short* __restrict__ Wm1T,
    const unsigned short* __restrict__ arena, const unsigned short* __restrict__ eaC,
    const int* __restrict__ eid, const int* __restrict__ flag,
    void* __restrict__ out) {
  __shared__ int4 sm4[128 * 33];
  char* smc = (char*)sm4;
  const long tileBase = (long)blockIdx.x * 128;
  stage_tile<true>(smc, e, tileBase, N_EDGES - 1);
  __syncthreads();
  fp32x4 acc[2][8];
#pragma unroll
  for (int mt = 0; mt < 2; ++mt)
#pragma unroll
    for (int nt = 0; nt < 8; ++nt) acc[mt][nt] = 0.f;
  const int tid = threadIdx.x, wave = tid >> 6, lane = tid & 63;
  const int q = lane >> 4, ll = lane & 15;
  const int colBase = wave * 32;
  gemm_swap<2>(smc, Wm1T, colBase, acc);

  float alphaf = bf2f(arena[A_AL]);
  float bmc[2][4], wl[2][4], w2c[2][4];
#pragma unroll
  for (int mt = 0; mt < 2; ++mt)
#pragma unroll
    for (int r = 0; r < 4; ++r) {
      int col = colBase + mt * 16 + q * 4 + r;
      bmc[mt][r] = bf2f(arena[A_BM1 + col]);
      wl[mt][r] = bf2f(arena[A_WM1 + 32768 + col]);
      w2c[mt][r] = bf2f(arena[A_WM2 + col]);
    }
  __syncthreads();             // before aliasing LDS as fp32 partials
  float* part = (float*)smc;   // [128][4]
#pragma unroll
  for (int nt = 0; nt < 8; ++nt) {
    int el = nt * 16 + ll;
    float eav = bf2f(eaC[tileBase + el]);
    float ps = 0.f;
#pragma unroll
    for (int mt = 0; mt < 2; ++mt)
#pragma unroll
      for (int r = 0; r < 4; ++r) {
        float h = acc[mt][nt][r] + bmc[mt][r] + eav * wl[mt][r];
        h = (h > 0.f) ? h : alphaf * h;
        ps += h * w2c[mt][r];
      }
    ps += __shfl_xor(ps, 16, 64);
    ps += __shfl_xor(ps, 32, 64);
    if (q == 0) part[el * 4 + wave] = ps;
  }
  __syncthreads();
  if (tid < 128) {
    float t = part[tid * 4] + part[tid * 4 + 1] + part[tid * 4 + 2] + part[tid * 4 + 3]
            + bf2f(arena[A_BM2]);
    long row = tileBase + tid;
    int oe = eid[row]; if ((unsigned)oe >= N_EDGES) oe = 0;
    if (*flag) ((float*)out)[oe] = t;
    else       ((unsigned short*)out)[oe] = f2bf(t);
  }
}

// ---------------------------------------------------------------------------
extern "C" void kernel_launch(void* const* d_in, const int* in_sizes, int n_in,
                              void* d_out, int out_size, void* d_ws, size_t ws_size,
                              hipStream_t stream) {
  const int* eidx = (const int*)d_in[2];
  const int* srcA = eidx;
  const int* dstA = eidx + N_EDGES;
  (void)in_sizes; (void)n_in; (void)out_size;

  char* ws = (char*)d_ws;
  size_t off = 0;
  auto alloc = [&](size_t bytes) -> char* {
    char* p = ws + off;
    off = (off + bytes + 255) & ~(size_t)255;
    return p;
  };
  unsigned short* e_buf   = (unsigned short*)alloc((size_t)N_EDGES * 256 * 2);  // 164 MB
  float*          xf      = (float*)alloc((size_t)N_NODES * 256 * 4);
  unsigned short* xbf     = (unsigned short*)alloc((size_t)N_NODES * 256 * 2);
  unsigned short* XW      = (unsigned short*)alloc((size_t)N_NODES * 1024 * 2);
  float*          agg     = (float*)alloc((size_t)N_NODES * 256 * 4);
  unsigned short* nodeBT  = (unsigned short*)alloc((size_t)917504 * 2);
  unsigned short* WeT     = (unsigned short*)alloc((size_t)4 * 65536 * 2);
  unsigned short* Wm1T    = (unsigned short*)alloc((size_t)32768 * 2);
  unsigned short* biascat = (unsigned short*)alloc((size_t)3584 * 2);
  unsigned short* arena   = (unsigned short*)alloc((size_t)ARENA_TOT * 2);
  int* deg    = (int*)alloc((size_t)N_NODES * 4);
  int* rowptr = (int*)alloc((size_t)(N_NODES + 1) * 4);
  int* cursor = (int*)alloc((size_t)N_NODES * 4);
  int* eid    = (int*)alloc((size_t)N_EDGES * 4);
  int* csrc   = (int*)alloc((size_t)N_EDGES * 4);
  int* cdst   = (int*)alloc((size_t)N_EDGES * 4);
  unsigned short* eaC = (unsigned short*)alloc((size_t)N_EDGES * 2);
  int* flag   = (int*)alloc(4);
  if (ws_size < off) return;  // distinctive signature: out stays all-zero

  Ptrs ptrs;
  {
    int map[19] = {0, 1, 3, 4, 5, 6, 7, 8, 9, 10, 11, 12, 13, 14, 15, 16, 17, 18, 19};
    for (int j = 0; j < 19; ++j) ptrs.p[j] = d_in[map[j]];
  }

  dim3 blk(256);
  k_detect<<<dim3(1), blk, 0, stream>>>((const unsigned short*)d_in[3], flag);
  k_cast<<<dim3((ARENA_USED + 255) / 256), blk, 0, stream>>>(ptrs, flag, arena);
  k_prep<<<dim3(256, 1, 20), blk, 0, stream>>>(arena, nodeBT, WeT, Wm1T, biascat);
  k_init_x<<<dim3(N_NODES), blk, 0, stream>>>(arena, xf, xbf);
  hipMemsetAsync(deg, 0, (size_t)N_NODES * 4, stream);
  k_hist<<<dim3(N_EDGES / 256), blk, 0, stream>>>(dstA, deg);
  k_scan<<<dim3(1), blk, 0, stream>>>(deg, rowptr, cursor);
  k_fill<<<dim3(N_EDGES / 256), blk, 0, stream>>>(dstA, srcA, arena, cursor, eid, csrc,
                                                  cdst, eaC);

  for (int l = 0; l < 3; ++l) {
    k_node_gemm<<<dim3(79, 4), blk, 0, stream>>>(xbf, nodeBT + l * 262144,
                                                 biascat + l * 1024, XW, 1024);
    if (l == 0)
      k_agg<true><<<dim3(N_NODES), blk, 0, stream>>>(rowptr, csrc, e_buf, eaC, arena,
                                                     XW, 1024, 256, agg);
    else
      k_agg<false><<<dim3(N_NODES), blk, 0, stream>>>(rowptr, csrc, e_buf, eaC, arena,
                                                      XW, 1024, 256, agg);
    if (l == 0)
      k_edge<true><<<dim3(N_EDGES / 128), blk, 0, stream>>>(e_buf, WeT + l * 65536, XW, 1024,
                                                            512, 768, arena + A_BE + l * 256,
                                                            arena, eaC, csrc, cdst);
    else
      k_edge<false><<<dim3(N_EDGES / 128), blk, 0, stream>>>(e_buf, WeT + l * 65536, XW, 1024,
                                                             512, 768, arena + A_BE + l * 256,
                                                             arena, eaC, csrc, cdst);
    k_node_update<<<dim3(N_NODES), blk, 0, stream>>>(xf, xbf, XW, agg);
  }
  // layer 3 (edge update only) + MLP head
  k_node_gemm<<<dim3(79, 2), blk, 0, stream>>>(xbf, nodeBT + 786432, biascat + 3072, XW, 512);
  k_edge<false><<<dim3(N_EDGES / 128), blk, 0, stream>>>(e_buf, WeT + 196608, XW, 512,
                                                         0, 256, arena + A_BE + 768,
                                                         arena, eaC, csrc, cdst);
  k_mlp<<<dim3(N_EDGES / 128), blk, 0, stream>>>(e_buf, Wm1T, arena, eaC, eid, flag, d_out);
}

// Round 7
// 1184.446 us; speedup vs baseline: 1.1759x; 1.1759x over previous
//
#include <hip/hip_runtime.h>
#include <stdint.h>

#define N_NODES 10000
#define N_EDGES 320000

using bf16x8 = __attribute__((ext_vector_type(8))) short;
using fp32x4 = __attribute__((ext_vector_type(4))) float;
using u16x4 = __attribute__((ext_vector_type(4))) unsigned short;
using u16x8 = __attribute__((ext_vector_type(8))) unsigned short;
using i32x4 = __attribute__((ext_vector_type(4))) int;

__device__ __forceinline__ float bf2f(unsigned short u) {
  union { unsigned int i; float f; } v; v.i = ((unsigned int)u) << 16; return v.f;
}
__device__ __forceinline__ unsigned short f2bf(float f) {
  union { float f; unsigned int i; } v; v.f = f;
  unsigned int x = v.i;
  x += 0x7fffu + ((x >> 16) & 1u);
  return (unsigned short)(x >> 16);
}

// ---------------- internal bf16 arena (element offsets) ---------------------
#define A_POS 0
#define A_EA 20000
#define A_WP 340000
#define A_BP 340512
#define A_WA 340768
#define A_BA 341024
#define A_W1 341280
#define A_B1 537888
#define A_W2 538656
#define A_B2 735264
#define A_WE 736032
#define A_BE 998176
#define A_WS 999200
#define A_WT 1261344
#define A_WM1 1523488
#define A_BM1 1556384
#define A_AL 1556512
#define A_WM2 1556544
#define A_BM2 1556672
#define ARENA_USED 1556673
#define ARENA_TOT 1556736

__constant__ int g_off[19] = {A_POS, A_EA, A_WP, A_BP, A_WA, A_BA, A_W1, A_B1,
                              A_W2, A_B2, A_WE, A_BE, A_WS, A_WT, A_WM1,
                              A_BM1, A_AL, A_WM2, A_BM2};

struct Ptrs { const void* p[19]; };

// Dtype detector: fp32 read as bf16 halves yields ~47% |v|>100; bf16 never.
__global__ void k_detect(const unsigned short* wpraw, int* flag) {
  __shared__ int cnt;
  int tid = threadIdx.x;
  if (tid == 0) cnt = 0;
  __syncthreads();
  float v0 = bf2f(wpraw[tid]);
  float v1 = bf2f(wpraw[256 + tid]);
  int big = (fabsf(v0) > 100.f ? 1 : 0) + (fabsf(v1) > 100.f ? 1 : 0);
  atomicAdd(&cnt, big);
  __syncthreads();
  if (tid == 0) *flag = (cnt > 10) ? 1 : 0;  // 1 = fp32 inputs
}

// Normalize all float inputs into the bf16 arena (flattened grid).
__global__ void k_cast(Ptrs ptrs, const int* __restrict__ flag,
                       unsigned short* __restrict__ arena) {
  int a = blockIdx.x * 256 + threadIdx.x;
  if (a >= ARENA_USED) return;
  int z = 0;
#pragma unroll
  for (int j = 1; j < 19; ++j) if (a >= g_off[j]) z = j;
  int i = a - g_off[z];
  float v;
  if (*flag) v = ((const float*)ptrs.p[z])[i];
  else       v = bf2f(((const unsigned short*)ptrs.p[z])[i]);
  arena[a] = f2bf(v);
}

// ---------------------------------------------------------------------------
// Weight prep: transpose [K,N] -> n-major [N,K] (row = out-col, 512B rows).
// nodeBT per layer l<3: [W1T|W2T|WsT|WtT] (1024x256); l==3: [WsT|WtT].
// ---------------------------------------------------------------------------
__global__ void k_prep(const unsigned short* __restrict__ arena,
                       unsigned short* nodeBT, unsigned short* WeT,
                       unsigned short* Wm1T, unsigned short* biascat) {
  int z = blockIdx.z;
  int i = blockIdx.x * 256 + threadIdx.x;
  if (z == 19) {  // bias concat: 3 x [b1|b2|0|0] (1024) then 512 zeros
    if (i < 3072) {
      int l = i >> 10, j = i & 1023;
      unsigned short v = 0;
      if (j < 256) v = arena[A_B1 + l * 256 + j];
      else if (j < 512) v = arena[A_B2 + l * 256 + (j - 256)];
      biascat[i] = v;
    } else if (i < 3584) {
      biascat[i] = 0;
    }
    return;
  }
  const unsigned short* src; unsigned short* dst; int srcN = 256;
  if (z < 3)       {                 src = arena + A_W1 + z * 65536; dst = nodeBT + z * 262144; }
  else if (z < 6)  { int l = z - 3;  src = arena + A_W2 + l * 65536; dst = nodeBT + l * 262144 + 65536; }
  else if (z < 10) { int l = z - 6;  src = arena + A_WS + l * 65536;
                     dst = (l < 3) ? nodeBT + l * 262144 + 131072 : nodeBT + 786432; }
  else if (z < 14) { int l = z - 10; src = arena + A_WT + l * 65536;
                     dst = (l < 3) ? nodeBT + l * 262144 + 196608 : nodeBT + 786432 + 65536; }
  else if (z < 18) { int l = z - 14; src = arena + A_WE + l * 65536; dst = WeT + l * 65536; }
  else             { src = arena + A_WM1; dst = Wm1T; srcN = 128; }
  if (i < srcN * 256) {
    int k = i & 255, n = i >> 8;
    dst[i] = src[k * srcN + n];  // dst[n][k] = src[k][n]
  }
}

// x0 = pos @ Wp + bp (K=2), fp32 master + bf16 copy
__global__ void k_init_x(const unsigned short* __restrict__ arena,
                         float* __restrict__ xf, unsigned short* __restrict__ xbf) {
  int n = blockIdx.x, c = threadIdx.x;
  float p0 = bf2f(arena[A_POS + 2 * n]), p1 = bf2f(arena[A_POS + 2 * n + 1]);
  float v = fmaf(p0, bf2f(arena[A_WP + c]),
                 fmaf(p1, bf2f(arena[A_WP + 256 + c]), bf2f(arena[A_BP + c])));
  long idx = ((long)n << 8) + c;
  xf[idx] = v;
  xbf[idx] = f2bf(v);
}

// ---------------- CSR build (by dst). e lives in CSR row order everywhere ---
__global__ void k_hist(const int* __restrict__ dstA, int* __restrict__ deg) {
  int i = blockIdx.x * 256 + threadIdx.x;
  if (i < N_EDGES) {
    int d = dstA[i];
    if ((unsigned)d < N_NODES) atomicAdd(&deg[d], 1);
  }
}

__global__ void k_scan(const int* __restrict__ deg, int* __restrict__ rowptr,
                       int* __restrict__ cursor) {
  __shared__ int part[256];
  int tid = threadIdx.x;
  int base = tid * 40;
  int s = 0;
  for (int i = 0; i < 40; ++i) {
    int idx = base + i;
    if (idx < N_NODES) s += deg[idx];
  }
  part[tid] = s;
  __syncthreads();
  if (tid == 0) {
    int run = 0;
    for (int i = 0; i < 256; ++i) { int t = part[i]; part[i] = run; run += t; }
    rowptr[N_NODES] = run;
  }
  __syncthreads();
  int run = part[tid];
  for (int i = 0; i < 40; ++i) {
    int idx = base + i;
    if (idx < N_NODES) { rowptr[idx] = run; cursor[idx] = run; run += deg[idx]; }
  }
}

// Also emits csrc/cdst (endpoints in CSR order) and eaC (ea gathered to CSR).
__global__ void k_fill(const int* __restrict__ dstA, const int* __restrict__ srcA,
                       const unsigned short* __restrict__ arena,
                       int* __restrict__ cursor, int* __restrict__ eid,
                       int* __restrict__ csrc, int* __restrict__ cdst,
                       unsigned short* __restrict__ eaC) {
  int i = blockIdx.x * 256 + threadIdx.x;
  if (i < N_EDGES) {
    int d = dstA[i]; if ((unsigned)d >= N_NODES) d = 0;
    int p = atomicAdd(&cursor[d], 1);
    if ((unsigned)p < N_EDGES) {
      eid[p] = i;
      csrc[p] = srcA[i];
      cdst[p] = d;
      eaC[p] = arena[A_EA + i];
    }
  }
}

// ---------------------------------------------------------------------------
// Swapped-operand GEMM core with PERMUTED column mapping: A-frag lane ll of
// fragment mt loads WT row  oc = colBase + (ll>>2)*(MT*4) + mt*4 + (ll&3).
// Then lane (q,ll) reg r of frag mt holds out-col colBase + q*(MT*4) + mt*4+r
// -> each lane's (mt,r) values cover MT*4 CONSECUTIVE cols (32B for MT=4):
// epilogue gathers/stores become full-line 16B chunks (2x fewer L1 transac).
// B-frag: LDS tile row (n=ll). D row = nt*16+ll.
// LDS pitch 528B -> <=2-way bank aliasing (free, m136).
// ---------------------------------------------------------------------------
#define SM_PITCH 528

template <bool NT>
__device__ __forceinline__ void stage_tile(char* smc, const unsigned short* src,
                                           long rowBase, long maxRow) {
  int tid = threadIdx.x;
#pragma unroll
  for (int it = 0; it < 16; ++it) {
    int lin = it * 256 + tid;       // 128 rows x 32 groups of 16B
    int row = lin >> 5, g = lin & 31;
    long rg = rowBase + row;
    if (rg > maxRow) rg = maxRow;
    const i32x4* p = (const i32x4*)((const char*)src + (rg << 9) + (g << 4));
    i32x4 v = NT ? __builtin_nontemporal_load(p) : *p;
    *(i32x4*)(smc + row * SM_PITCH + (g << 4)) = v;
  }
}

template <int MT>
__device__ __forceinline__ void gemm_swap(const char* smc, const unsigned short* WT,
                                          int colBase, fp32x4 (&acc)[MT][8]) {
  const int lane = threadIdx.x & 63;
  const int q = lane >> 4, ll = lane & 15;
  const int llperm = ((ll >> 2) * (MT * 4)) + (ll & 3);  // permuted col offset
#pragma unroll
  for (int ks = 0; ks < 8; ++ks) {
    bf16x8 a[MT];
#pragma unroll
    for (int mt = 0; mt < MT; ++mt) {
      int oc = colBase + llperm + mt * 4;
      a[mt] = *(const bf16x8*)((const char*)WT + ((long)oc << 9) + (ks << 6) + (q << 4));
    }
    bf16x8 b[8];
#pragma unroll
    for (int nt = 0; nt < 8; ++nt)
      b[nt] = *(const bf16x8*)(smc + (nt * 16 + ll) * SM_PITCH + (ks << 6) + (q << 4));
#pragma unroll
    for (int mt = 0; mt < MT; ++mt)
#pragma unroll
      for (int nt = 0; nt < 8; ++nt)
        acc[mt][nt] = __builtin_amdgcn_mfma_f32_16x16x32_bf16(a[mt], b[nt], acc[mt][nt], 0, 0, 0);
  }
}

// ---------------------------------------------------------------------------
// Edge update (CSR row order): e = e + relu(e @ We + XWs[src] + XWt[dst] + be).
// Epilogue: each lane owns 16 consecutive cols [cb, cb+16), cb=colBase+q*16 ->
// xs/xt gathers and LDS er r/w are 2x16B chunks (full-line transactions).
// Results written back into the LDS tile, then one coalesced full-line NT
// writeback (no partial-line write amplification).
// FIRST: e0 = eaC*Wa+ba built directly in LDS.
// ---------------------------------------------------------------------------
template <bool FIRST>
__global__ __launch_bounds__(256, 2) void k_edge(
    unsigned short* __restrict__ e, const unsigned short* __restrict__ WT,
    const unsigned short* __restrict__ XW, int xw_pitch, int xs_off, int xt_off,
    const unsigned short* __restrict__ bePtr, const unsigned short* __restrict__ arena,
    const unsigned short* __restrict__ eaC,
    const int* __restrict__ csrc, const int* __restrict__ cdst) {
  __shared__ int4 sm4[128 * 33];
  char* smc = (char*)sm4;
  const long tileBase = (long)blockIdx.x * 128;
  const int tid = threadIdx.x;

  if (FIRST) {
#pragma unroll
    for (int it = 0; it < 16; ++it) {
      int lin = it * 256 + tid;
      int row = lin >> 5, g = lin & 31;
      float eav = bf2f(eaC[tileBase + row]);
      int c0 = g * 8;
      bf16x8 ov;
#pragma unroll
      for (int j = 0; j < 8; ++j) {
        float f = fmaf(eav, bf2f(arena[A_WA + c0 + j]), bf2f(arena[A_BA + c0 + j]));
        ((unsigned short*)&ov)[j] = f2bf(f);
      }
      *(bf16x8*)(smc + row * SM_PITCH + (g << 4)) = ov;
    }
  } else {
    stage_tile<true>(smc, e, tileBase, N_EDGES - 1);
  }
  __syncthreads();

  fp32x4 acc[4][8];
#pragma unroll
  for (int mt = 0; mt < 4; ++mt)
#pragma unroll
    for (int nt = 0; nt < 8; ++nt) acc[mt][nt] = 0.f;

  const int wave = tid >> 6, lane = tid & 63;
  const int q = lane >> 4, ll = lane & 15;
  const int colBase = wave * 64;
  gemm_swap<4>(smc, WT, colBase, acc);

  const int cb = colBase + q * 16;  // this lane's 16 consecutive cols
  float bec[16];
#pragma unroll
  for (int i = 0; i < 16; ++i) bec[i] = bf2f(bePtr[cb + i]);

#pragma unroll
  for (int nt = 0; nt < 8; ++nt) {
    int el = nt * 16 + ll;
    long edge = tileBase + el;
    int sn = csrc[edge]; if ((unsigned)sn >= N_NODES) sn = 0;
    int dn = cdst[edge]; if ((unsigned)dn >= N_NODES) dn = 0;
    const unsigned short* xsrow = XW + (long)sn * xw_pitch + xs_off + cb;
    const unsigned short* xtrow = XW + (long)dn * xw_pitch + xt_off + cb;
    u16x8 xs0 = *(const u16x8*)(xsrow);
    u16x8 xs1 = *(const u16x8*)(xsrow + 8);
    u16x8 xt0 = *(const u16x8*)(xtrow);
    u16x8 xt1 = *(const u16x8*)(xtrow + 8);
    u16x8* slot = (u16x8*)(smc + el * SM_PITCH + cb * 2);
    u16x8 er0 = slot[0], er1 = slot[1];
    u16x8 o0, o1;
#pragma unroll
    for (int mt = 0; mt < 4; ++mt)
#pragma unroll
      for (int r = 0; r < 4; ++r) {
        int i = mt * 4 + r;
        float xsv = bf2f(i < 8 ? xs0[i] : xs1[i - 8]);
        float xtv = bf2f(i < 8 ? xt0[i] : xt1[i - 8]);
        float erv = bf2f(i < 8 ? er0[i] : er1[i - 8]);
        float v = acc[mt][nt][r] + xsv + xtv + bec[i];
        v = fmaxf(v, 0.f);
        unsigned short ob = f2bf(erv + v);
        if (i < 8) o0[i] = ob; else o1[i - 8] = ob;
      }
    slot[0] = o0;
    slot[1] = o1;  // update LDS in place (slot owned by this lane only)
  }
  __syncthreads();
  // Coalesced full-line writeback: 16B/lane, 1KB contiguous per instruction.
#pragma unroll
  for (int it = 0; it < 16; ++it) {
    int lin = it * 256 + tid;
    int row = lin >> 5, g = lin & 31;
    i32x4 v = *(const i32x4*)(smc + row * SM_PITCH + (g << 4));
    __builtin_nontemporal_store(v, (i32x4*)((char*)e + ((tileBase + row) << 9) + (g << 4)));
  }
}

// Node-side GEMM: XW = x_bf @ [W1|W2|Ws|Wt] (+b1|b2|0|0), bf16 out.
__global__ __launch_bounds__(256, 2) void k_node_gemm(
    const unsigned short* __restrict__ xbf, const unsigned short* __restrict__ WT,
    const unsigned short* __restrict__ bias, unsigned short* __restrict__ out,
    int out_pitch) {
  __shared__ int4 sm4[128 * 33];
  char* smc = (char*)sm4;
  const long tileBase = (long)blockIdx.x * 128;
  stage_tile<false>(smc, xbf, tileBase, N_NODES - 1);
  __syncthreads();
  fp32x4 acc[4][8];
#pragma unroll
  for (int mt = 0; mt < 4; ++mt)
#pragma unroll
    for (int nt = 0; nt < 8; ++nt) acc[mt][nt] = 0.f;
  const int tid = threadIdx.x, wave = tid >> 6, lane = tid & 63;
  const int q = lane >> 4, ll = lane & 15;
  const int colBase = blockIdx.y * 256 + wave * 64;
  gemm_swap<4>(smc, WT, colBase, acc);

  const int cb = colBase + q * 16;
  float bs[16];
#pragma unroll
  for (int i = 0; i < 16; ++i) bs[i] = bf2f(bias[cb + i]);

#pragma unroll
  for (int nt = 0; nt < 8; ++nt) {
    long nn = tileBase + nt * 16 + ll;
    if (nn >= N_NODES) continue;
    u16x8 o0, o1;
#pragma unroll
    for (int mt = 0; mt < 4; ++mt)
#pragma unroll
      for (int r = 0; r < 4; ++r) {
        int i = mt * 4 + r;
        unsigned short ob = f2bf(acc[mt][nt][r] + bs[i]);
        if (i < 8) o0[i] = ob; else o1[i - 8] = ob;
      }
    unsigned short* orow = out + nn * out_pitch + cb;
    *(u16x8*)(orow) = o0;
    *(u16x8*)(orow + 8) = o1;
  }
}

// agg[n] = sum_{CSR rows j of n} sigmoid(e[j]) * XW2[csrc[j]] — e sequential.
template <bool FIRST>
__global__ void k_agg(const int* __restrict__ rowptr, const int* __restrict__ csrc,
                      const unsigned short* __restrict__ e,
                      const unsigned short* __restrict__ eaC,
                      const unsigned short* __restrict__ arena,
                      const unsigned short* __restrict__ XW, int xw_pitch, int x2_off,
                      float* __restrict__ agg) {
  int n = blockIdx.x, c = threadIdx.x;
  int j0 = rowptr[n], j1 = rowptr[n + 1];
  float wac = 0.f, bac = 0.f;
  if (FIRST) { wac = bf2f(arena[A_WA + c]); bac = bf2f(arena[A_BA + c]); }
  float acc = 0.f;
  for (int j = j0; j < j1; ++j) {
    int sn = csrc[j]; if ((unsigned)sn >= N_NODES) sn = 0;
    float ev;
    if (FIRST) ev = fmaf(bf2f(eaC[j]), wac, bac);
    else ev = bf2f(__builtin_nontemporal_load(e + ((long)j << 8) + c));
    float gate = 1.f / (1.f + __expf(-ev));
    acc += gate * bf2f(XW[(long)sn * xw_pitch + x2_off + c]);
  }
  agg[((long)n << 8) + c] = acc;
}

// x += relu(xW1+b1 + agg); refresh bf16 copy
__global__ void k_node_update(float* __restrict__ xf, unsigned short* __restrict__ xbf,
                              const unsigned short* __restrict__ XW,
                              const float* __restrict__ agg) {
  int n = blockIdx.x, c = threadIdx.x;
  long idx = ((long)n << 8) + c;
  float t = bf2f(XW[((long)n << 10) + c]) + agg[idx];
  float nx = xf[idx] + fmaxf(t, 0.f);
  xf[idx] = nx;
  xbf[idx] = f2bf(nx);
}

// Final MLP (CSR rows): out[eid[j]] = prelu(e@Wm1[:256]+eaC*Wm1[256]+bm1)@Wm2+bm2
__global__ __launch_bounds__(256, 2) void k_mlp(
    const unsigned short* __restrict__ e, const unsigned short* __restrict__ Wm1T,
    const unsigned short* __restrict__ arena, const unsigned short* __restrict__ eaC,
    const int* __restrict__ eid, const int* __restrict__ flag,
    void* __restrict__ out) {
  __shared__ int4 sm4[128 * 33];
  char* smc = (char*)sm4;
  const long tileBase = (long)blockIdx.x * 128;
  stage_tile<true>(smc, e, tileBase, N_EDGES - 1);
  __syncthreads();
  fp32x4 acc[2][8];
#pragma unroll
  for (int mt = 0; mt < 2; ++mt)
#pragma unroll
    for (int nt = 0; nt < 8; ++nt) acc[mt][nt] = 0.f;
  const int tid = threadIdx.x, wave = tid >> 6, lane = tid & 63;
  const int q = lane >> 4, ll = lane & 15;
  const int colBase = wave * 32;
  gemm_swap<2>(smc, Wm1T, colBase, acc);

  const int cb = colBase + q * 8;  // 8 consecutive out-cols per lane (MT=2)
  float alphaf = bf2f(arena[A_AL]);
  float bmc[8], wl[8], w2c[8];
#pragma unroll
  for (int i = 0; i < 8; ++i) {
    bmc[i] = bf2f(arena[A_BM1 + cb + i]);
    wl[i] = bf2f(arena[A_WM1 + 32768 + cb + i]);
    w2c[i] = bf2f(arena[A_WM2 + cb + i]);
  }
  __syncthreads();             // before aliasing LDS as fp32 partials
  float* part = (float*)smc;   // [128][4]
#pragma unroll
  for (int nt = 0; nt < 8; ++nt) {
    int el = nt * 16 + ll;
    float eav = bf2f(eaC[tileBase + el]);
    float ps = 0.f;
#pragma unroll
    for (int mt = 0; mt < 2; ++mt)
#pragma unroll
      for (int r = 0; r < 4; ++r) {
        int i = mt * 4 + r;
        float h = acc[mt][nt][r] + bmc[i] + eav * wl[i];
        h = (h > 0.f) ? h : alphaf * h;
        ps += h * w2c[i];
      }
    ps += __shfl_xor(ps, 16, 64);
    ps += __shfl_xor(ps, 32, 64);
    if (q == 0) part[el * 4 + wave] = ps;
  }
  __syncthreads();
  if (tid < 128) {
    float t = part[tid * 4] + part[tid * 4 + 1] + part[tid * 4 + 2] + part[tid * 4 + 3]
            + bf2f(arena[A_BM2]);
    long row = tileBase + tid;
    int oe = eid[row]; if ((unsigned)oe >= N_EDGES) oe = 0;
    if (*flag) ((float*)out)[oe] = t;
    else       ((unsigned short*)out)[oe] = f2bf(t);
  }
}

// ---------------------------------------------------------------------------
extern "C" void kernel_launch(void* const* d_in, const int* in_sizes, int n_in,
                              void* d_out, int out_size, void* d_ws, size_t ws_size,
                              hipStream_t stream) {
  const int* eidx = (const int*)d_in[2];
  const int* srcA = eidx;
  const int* dstA = eidx + N_EDGES;
  (void)in_sizes; (void)n_in; (void)out_size;

  char* ws = (char*)d_ws;
  size_t off = 0;
  auto alloc = [&](size_t bytes) -> char* {
    char* p = ws + off;
    off = (off + bytes + 255) & ~(size_t)255;
    return p;
  };
  unsigned short* e_buf   = (unsigned short*)alloc((size_t)N_EDGES * 256 * 2);  // 164 MB
  float*          xf      = (float*)alloc((size_t)N_NODES * 256 * 4);
  unsigned short* xbf     = (unsigned short*)alloc((size_t)N_NODES * 256 * 2);
  unsigned short* XW      = (unsigned short*)alloc((size_t)N_NODES * 1024 * 2);
  float*          agg     = (float*)alloc((size_t)N_NODES * 256 * 4);
  unsigned short* nodeBT  = (unsigned short*)alloc((size_t)917504 * 2);
  unsigned short* WeT     = (unsigned short*)alloc((size_t)4 * 65536 * 2);
  unsigned short* Wm1T    = (unsigned short*)alloc((size_t)32768 * 2);
  unsigned short* biascat = (unsigned short*)alloc((size_t)3584 * 2);
  unsigned short* arena   = (unsigned short*)alloc((size_t)ARENA_TOT * 2);
  int* deg    = (int*)alloc((size_t)N_NODES * 4);
  int* rowptr = (int*)alloc((size_t)(N_NODES + 1) * 4);
  int* cursor = (int*)alloc((size_t)N_NODES * 4);
  int* eid    = (int*)alloc((size_t)N_EDGES * 4);
  int* csrc   = (int*)alloc((size_t)N_EDGES * 4);
  int* cdst   = (int*)alloc((size_t)N_EDGES * 4);
  unsigned short* eaC = (unsigned short*)alloc((size_t)N_EDGES * 2);
  int* flag   = (int*)alloc(4);
  if (ws_size < off) return;  // distinctive signature: out stays all-zero

  Ptrs ptrs;
  {
    int map[19] = {0, 1, 3, 4, 5, 6, 7, 8, 9, 10, 11, 12, 13, 14, 15, 16, 17, 18, 19};
    for (int j = 0; j < 19; ++j) ptrs.p[j] = d_in[map[j]];
  }

  dim3 blk(256);
  k_detect<<<dim3(1), blk, 0, stream>>>((const unsigned short*)d_in[3], flag);
  k_cast<<<dim3((ARENA_USED + 255) / 256), blk, 0, stream>>>(ptrs, flag, arena);
  k_prep<<<dim3(256, 1, 20), blk, 0, stream>>>(arena, nodeBT, WeT, Wm1T, biascat);
  k_init_x<<<dim3(N_NODES), blk, 0, stream>>>(arena, xf, xbf);
  hipMemsetAsync(deg, 0, (size_t)N_NODES * 4, stream);
  k_hist<<<dim3(N_EDGES / 256), blk, 0, stream>>>(dstA, deg);
  k_scan<<<dim3(1), blk, 0, stream>>>(deg, rowptr, cursor);
  k_fill<<<dim3(N_EDGES / 256), blk, 0, stream>>>(dstA, srcA, arena, cursor, eid, csrc,
                                                  cdst, eaC);

  for (int l = 0; l < 3; ++l) {
    k_node_gemm<<<dim3(79, 4), blk, 0, stream>>>(xbf, nodeBT + l * 262144,
                                                 biascat + l * 1024, XW, 1024);
    if (l == 0)
      k_agg<true><<<dim3(N_NODES), blk, 0, stream>>>(rowptr, csrc, e_buf, eaC, arena,
                                                     XW, 1024, 256, agg);
    else
      k_agg<false><<<dim3(N_NODES), blk, 0, stream>>>(rowptr, csrc, e_buf, eaC, arena,
                                                      XW, 1024, 256, agg);
    if (l == 0)
      k_edge<true><<<dim3(N_EDGES / 128), blk, 0, stream>>>(e_buf, WeT + l * 65536, XW, 1024,
                                                            512, 768, arena + A_BE + l * 256,
                                                            arena, eaC, csrc, cdst);
    else
      k_edge<false><<<dim3(N_EDGES / 128), blk, 0, stream>>>(e_buf, WeT + l * 65536, XW, 1024,
                                                             512, 768, arena + A_BE + l * 256,
                                                             arena, eaC, csrc, cdst);
    k_node_update<<<dim3(N_NODES), blk, 0, stream>>>(xf, xbf, XW, agg);
  }
  // layer 3 (edge update only) + MLP head
  k_node_gemm<<<dim3(79, 2), blk, 0, stream>>>(xbf, nodeBT + 786432, biascat + 3072, XW, 512);
  k_edge<false><<<dim3(N_EDGES / 128), blk, 0, stream>>>(e_buf, WeT + 196608, XW, 512,
                                                         0, 256, arena + A_BE + 768,
                                                         arena, eaC, csrc, cdst);
  k_mlp<<<dim3(N_EDGES / 128), blk, 0, stream>>>(e_buf, Wm1T, arena, eaC, eid, flag, d_out);
}